// Round 19
// baseline (2072.339 us; speedup 1.0000x reference)
//
#include <hip/hip_runtime.h>
#include <hip/hip_bf16.h>

// Problem constants (match reference).
#define VOCAB  50257
#define D_EMB  128
#define HID    256
#define N_CLS  2
#define BSZ    256
#define T_LEN  2048
#define WSTR   132     // W_lds row stride in f32 (128 + 4 pad; 16B-aligned,
                       // phase shift 4 banks/row -> optimal W-read banking)

// ---------------------------------------------------------------------------
// Kernel 1: tab[v][j] = sum_d emb_table[v][d] * wx_w[d][j] + wx_b[j] + wh_b[j]
// ---------------------------------------------------------------------------
__global__ __launch_bounds__(256)
void tabax_kernel(const float* __restrict__ emb,
                  const float* __restrict__ wxw,
                  const float* __restrict__ wxb,
                  const float* __restrict__ whb,
                  float* __restrict__ tab)
{
    const int j  = threadIdx.x;          // output unit 0..255
    const int v0 = blockIdx.x * 32;
    const int rows = min(32, VOCAB - v0);

    __shared__ float ebuf[32 * D_EMB];   // 16 KB
    for (int i = j; i < rows * D_EMB; i += 256)
        ebuf[i] = emb[(size_t)v0 * D_EMB + i];
    __syncthreads();

    float acc[32];
#pragma unroll
    for (int r = 0; r < 32; ++r) acc[r] = 0.f;

#pragma unroll 8
    for (int d = 0; d < D_EMB; ++d) {
        float wxv = wxw[d * HID + j];    // coalesced
#pragma unroll
        for (int r = 0; r < 32; ++r)
            acc[r] = fmaf(ebuf[r * D_EMB + d], wxv, acc[r]); // LDS broadcast
    }

    const float bb = wxb[j] + whb[j];
    for (int r = 0; r < rows; ++r)
        tab[(size_t)(v0 + r) * HID + j] = acc[r] + bb;       // coalesced
}

__device__ __forceinline__ float fast_tanh(float x) {
    float e2 = __expf(2.f * x);
    return 1.f - 2.f / (e2 + 1.f);
}

// Pure-VALU 16-lane reduction (verified R18: -12%): DPP row_ror adds.
#define DPP_RADD(ACC, N)                                                    \
    asm("v_add_f32 %0, %0, %0 row_ror:" #N " row_mask:0xf bank_mask:0xf"    \
        : "+v"(ACC))

// ---------------------------------------------------------------------------
// Kernel 2 (main): one block per batch row, 1024 threads (16 waves, 4/SIMD).
// Thread (cg = tid>>4, kg = tid&15) owns cols [cg*4, cg*4+4) over k in
// [kg*8, kg*8+8) (lower, W from LDS) and [128+kg*8, 128+kg*8+8) (upper,
// W in registers).
//
// KEY CHANGE vs R18 (1366us): HALF of Whh now lives in LDS, transposed
// (wlds[col][k], stride 132 f32), read per step via ds_read_b128 -> lands
// directly in VGPRs (DS pipe, no AGPR stash possible). The register half
// shrinks to 32 f32/thread -- halving (or eliminating) the per-step
// v_accvgpr_read tax that R11-R18 counters implied (~64 copies/step).
// LDS: 135 KB W + 2 KB h + 2 KB scratch = 139 KB (<160 KB; >64 KB static
// is fine on gfx950 -- AITER uses 160 KB).
// W-read banking: phase = 16*(cg&1) + 8*(kg&3) + 4*cc -> 8 uniform
// quad-groups x 8 addrs = optimal 8-cycle wave reads.
// ---------------------------------------------------------------------------
__global__ __launch_bounds__(1024, 1)
void rnn_main_kernel(const int*   __restrict__ batch,
                     const float* __restrict__ whw,
                     const float* __restrict__ clfw,
                     const float* __restrict__ clfb,
                     const float* __restrict__ ax_tab,
                     float*       __restrict__ out)
{
    const int b   = blockIdx.x;
    const int tid = threadIdx.x;
    const int kg  = tid & 15;            // k-subrange selector
    const int cg  = tid >> 4;            // col-group: cols [cg*4, cg*4+4)
    const int c0  = cg * 4;
    const int q   = kg & 3;              // which of the 4 cols this lane picks

    __shared__ float wlds[256 * WSTR];   // W[k<128] transposed: wlds[c][k]
    __shared__ float hbuf[2][HID];       // double-buffered hidden state
    __shared__ float sbuf[2][HID];       // epilogue scratch

    // --- fill W_lds (transposed, one-time) ---
    for (int idx = tid; idx < 256 * 128; idx += 1024) {
        const int c = idx >> 7;
        const int k = idx & 127;
        wlds[c * WSTR + k] = whw[(size_t)k * HID + c];
    }

    // --- upper-half weights in registers: Wr[i][cc] = W[128+kg*8+i][c0+cc]
    float Wr[8][4];
#pragma unroll
    for (int i = 0; i < 8; ++i) {
        const int k = 128 + kg * 8 + i;
        const float4 w4 = *(const float4*)&whw[(size_t)k * HID + c0];
        Wr[i][0] = w4.x; Wr[i][1] = w4.y; Wr[i][2] = w4.z; Wr[i][3] = w4.w;
    }
#pragma unroll
    for (int i = 0; i < 8; ++i)
        asm volatile("" : "+v"(Wr[i][0]), "+v"(Wr[i][1]),
                          "+v"(Wr[i][2]), "+v"(Wr[i][3]));

    // loop-invariant W_lds bases for this thread's 4 columns
    const float* wl[4];
#pragma unroll
    for (int cc = 0; cc < 4; ++cc)
        wl[cc] = &wlds[(c0 + cc) * WSTR + kg * 8];

    const int  mycol = c0 + q;           // column this lane selects / writes
    const bool wr    = (kg < 4);         // lanes 0..3 of each row write

    if (tid < HID) hbuf[0][tid] = 0.f;

    const int* brow = batch + (size_t)b * T_LEN;
    const float* axp = ax_tab + mycol;   // 32-bit offsets: tok*256 elems
    int tok_n = brow[0];
    float axv = axp[(unsigned)tok_n * 256u];           // ax for t=0
    tok_n = brow[1];
    __syncthreads();

#define RNN_STEP(CUR, NXT, TT)                                              \
    {                                                                       \
        const int tok_nn = ((TT) + 2 < T_LEN) ? brow[(TT) + 2] : 0;         \
        const float ax_n = axp[(unsigned)tok_n * 256u];                     \
        /* h fragments: lower k = kg*8..+8, upper k = 128+kg*8..+8 */       \
        const float4 hL0 = *(const float4*)&hbuf[CUR][kg * 8];              \
        const float4 hL1 = *(const float4*)&hbuf[CUR][kg * 8 + 4];          \
        const float4 hU0 = *(const float4*)&hbuf[CUR][128 + kg * 8];        \
        const float4 hU1 = *(const float4*)&hbuf[CUR][128 + kg * 8 + 4];    \
        float acc[4];                                                       \
        _Pragma("unroll")                                                   \
        for (int cc = 0; cc < 4; ++cc) {                                    \
            const float4 w0 = *(const float4*)(wl[cc]);                     \
            const float4 w1 = *(const float4*)(wl[cc] + 4);                 \
            float a;                                                        \
            a = hL0.x * w0.x;                                               \
            a = fmaf(hL0.y, w0.y, a);                                       \
            a = fmaf(hL0.z, w0.z, a);                                       \
            a = fmaf(hL0.w, w0.w, a);                                       \
            a = fmaf(hL1.x, w1.x, a);                                       \
            a = fmaf(hL1.y, w1.y, a);                                       \
            a = fmaf(hL1.z, w1.z, a);                                       \
            a = fmaf(hL1.w, w1.w, a);                                       \
            acc[cc] = a;                                                    \
        }                                                                   \
        const float hu[8] = {hU0.x, hU0.y, hU0.z, hU0.w,                    \
                             hU1.x, hU1.y, hU1.z, hU1.w};                   \
        _Pragma("unroll")                                                   \
        for (int i = 0; i < 8; ++i)                                         \
            _Pragma("unroll")                                               \
            for (int cc = 0; cc < 4; ++cc)                                  \
                acc[cc] = fmaf(hu[i], Wr[i][cc], acc[cc]);                  \
        /* DPP rotate-reduce over the 16-lane row: 4 independent chains */  \
        _Pragma("unroll")                                                   \
        for (int i = 0; i < 4; ++i) {                                       \
            DPP_RADD(acc[i], 8);                                            \
            DPP_RADD(acc[i], 4);                                            \
            DPP_RADD(acc[i], 2);                                            \
            DPP_RADD(acc[i], 1);                                            \
        }                                                                   \
        /* loop-invariant-mask selects: lane takes acc[q] */                \
        const float r01 = (q & 1) ? acc[1] : acc[0];                        \
        const float r23 = (q & 1) ? acc[3] : acc[2];                        \
        const float res = (q & 2) ? r23 : r01;                              \
        const float hnew = fast_tanh(res + axv);                            \
        if (wr) hbuf[NXT][mycol] = hnew;                                    \
        __syncthreads();                                                    \
        axv   = ax_n;                                                       \
        tok_n = tok_nn;                                                     \
    }

    for (int t = 0; t < T_LEN; t += 2) {
        RNN_STEP(0, 1, t)
        RNN_STEP(1, 0, t + 1)
    }
#undef RNN_STEP

    // --- epilogue: out[b][c] = sum_j h[j] * clf_w[j][c] + clf_b[c] ---
    // After an even number of steps the final h is in hbuf[0].
    if (tid < HID) {
        const float h = hbuf[0][tid];
        sbuf[0][tid] = h * clfw[tid * N_CLS + 0];
        sbuf[1][tid] = h * clfw[tid * N_CLS + 1];
    }
    __syncthreads();
    if (tid < 64) {
        float v = sbuf[0][tid] + sbuf[0][tid + 64] +
                  sbuf[0][tid + 128] + sbuf[0][tid + 192];
#pragma unroll
        for (int off = 32; off > 0; off >>= 1) v += __shfl_xor(v, off);
        if (tid == 0) out[b * N_CLS + 0] = v + clfb[0];
    } else if (tid < 128) {
        const int l = tid - 64;
        float v = sbuf[1][l] + sbuf[1][l + 64] +
                  sbuf[1][l + 128] + sbuf[1][l + 192];
#pragma unroll
        for (int off = 32; off > 0; off >>= 1) v += __shfl_xor(v, off);
        if (l == 0) out[b * N_CLS + 1] = v + clfb[1];
    }
}

// ---------------------------------------------------------------------------
// Fallback (workspace too small for the 51.5 MB table).
// ---------------------------------------------------------------------------
__global__ __launch_bounds__(512, 2)
void rnn_fallback_kernel(const int*   __restrict__ batch,
                         const float* __restrict__ emb,
                         const float* __restrict__ wxw,
                         const float* __restrict__ wxb,
                         const float* __restrict__ whw,
                         const float* __restrict__ whb,
                         const float* __restrict__ clfw,
                         const float* __restrict__ clfb,
                         float*       __restrict__ out)
{
    const int b    = blockIdx.x;
    const int tid  = threadIdx.x;
    const int j    = tid >> 1;
    const int half = tid & 1;
    const int k0   = half * 128;

    __shared__ float hbuf[2][HID];
    __shared__ float ebuf[2][D_EMB];

    float w[128];
#pragma unroll
    for (int k = 0; k < 128; ++k)
        w[k] = whw[(size_t)(k0 + k) * HID + j];

    float wx[64];
#pragma unroll
    for (int d = 0; d < 64; ++d)
        wx[d] = wxw[(size_t)(half * 64 + d) * HID + j];

    const float bj  = whb[j];
    const float axb = wxb[j];

    if (tid < HID) hbuf[0][tid] = 0.f;

    const int* brow = batch + (size_t)b * T_LEN;

    int tok_n = brow[0];
    if (tid < D_EMB) ebuf[0][tid] = emb[(size_t)tok_n * D_EMB + tid];
    tok_n = brow[1];
    __syncthreads();

    float h_j = 0.f;
    int cur = 0;
    for (int t = 0; t < T_LEN; ++t) {
        const int nxt = cur ^ 1;
        const int tok_nn = (t + 2 < T_LEN) ? brow[t + 2] : 0;
        float ev = 0.f;
        if (t + 1 < T_LEN && tid < D_EMB)
            ev = emb[(size_t)tok_n * D_EMB + tid];

        float a0 = 0.f, a1 = 0.f, a2 = 0.f, a3 = 0.f;
        const float4* hv = (const float4*)&hbuf[cur][k0];
#pragma unroll
        for (int i = 0; i < 32; ++i) {
            float4 h4 = hv[i];
            a0 = fmaf(h4.x, w[4 * i + 0], a0);
            a1 = fmaf(h4.y, w[4 * i + 1], a1);
            a2 = fmaf(h4.z, w[4 * i + 2], a2);
            a3 = fmaf(h4.w, w[4 * i + 3], a3);
        }
        const float4* evv = (const float4*)&ebuf[cur][half * 64];
#pragma unroll
        for (int i = 0; i < 16; ++i) {
            float4 e4 = evv[i];
            a0 = fmaf(e4.x, wx[4 * i + 0], a0);
            a1 = fmaf(e4.y, wx[4 * i + 1], a1);
            a2 = fmaf(e4.z, wx[4 * i + 2], a2);
            a3 = fmaf(e4.w, wx[4 * i + 3], a3);
        }
        float s = (a0 + a1) + (a2 + a3);
        s += __shfl_xor(s, 1);

        h_j = fast_tanh(s + bj + axb);

        if (half == 0) hbuf[nxt][j] = h_j;
        if (t + 1 < T_LEN && tid < D_EMB) ebuf[nxt][tid] = ev;
        __syncthreads();

        tok_n = tok_nn;
        cur   = nxt;
    }

    if (half == 0) {
        hbuf[0][j] = h_j * clfw[j * N_CLS + 0];
        hbuf[1][j] = h_j * clfw[j * N_CLS + 1];
    }
    __syncthreads();
    if (tid < 64) {
        float v = hbuf[0][tid] + hbuf[0][tid + 64] +
                  hbuf[0][tid + 128] + hbuf[0][tid + 192];
#pragma unroll
        for (int off = 32; off > 0; off >>= 1) v += __shfl_xor(v, off);
        if (tid == 0) out[b * N_CLS + 0] = v + clfb[0];
    } else if (tid < 128) {
        const int l = tid - 64;
        float v = hbuf[1][l] + hbuf[1][l + 64] +
                  hbuf[1][l + 128] + hbuf[1][l + 192];
#pragma unroll
        for (int off = 32; off > 0; off >>= 1) v += __shfl_xor(v, off);
        if (l == 0) out[b * N_CLS + 1] = v + clfb[1];
    }
}

// ---------------------------------------------------------------------------
extern "C" void kernel_launch(void* const* d_in, const int* in_sizes, int n_in,
                              void* d_out, int out_size, void* d_ws, size_t ws_size,
                              hipStream_t stream)
{
    const int*   batch = (const int*)  d_in[0];
    const float* emb   = (const float*)d_in[1];
    const float* wxw   = (const float*)d_in[2];
    const float* wxb   = (const float*)d_in[3];
    const float* whw   = (const float*)d_in[4];
    const float* whb   = (const float*)d_in[5];
    const float* clfw  = (const float*)d_in[6];
    const float* clfb  = (const float*)d_in[7];
    float* out = (float*)d_out;

    const size_t tab_bytes = (size_t)VOCAB * HID * sizeof(float);
    if (ws_size >= tab_bytes) {
        float* tab = (float*)d_ws;
        tabax_kernel<<<(VOCAB + 31) / 32, 256, 0, stream>>>(emb, wxw, wxb, whb, tab);
        rnn_main_kernel<<<BSZ, 1024, 0, stream>>>(batch, whw, clfw, clfb, tab, out);
    } else {
        rnn_fallback_kernel<<<BSZ, 512, 0, stream>>>(batch, emb, wxw, wxb, whw, whb,
                                                     clfw, clfb, out);
    }
}

// Round 20
// 1403.838 us; speedup vs baseline: 1.4762x; 1.4762x over previous
//
#include <hip/hip_runtime.h>
#include <hip/hip_bf16.h>

// Problem constants (match reference).
#define VOCAB  50257
#define D_EMB  128
#define HID    256
#define N_CLS  2
#define BSZ    256
#define T_LEN  2048

// ---------------------------------------------------------------------------
// Kernel 1: tab[v][j] = sum_d emb_table[v][d] * wx_w[d][j] + wx_b[j] + wh_b[j]
// ---------------------------------------------------------------------------
__global__ __launch_bounds__(256)
void tabax_kernel(const float* __restrict__ emb,
                  const float* __restrict__ wxw,
                  const float* __restrict__ wxb,
                  const float* __restrict__ whb,
                  float* __restrict__ tab)
{
    const int j  = threadIdx.x;          // output unit 0..255
    const int v0 = blockIdx.x * 32;
    const int rows = min(32, VOCAB - v0);

    __shared__ float ebuf[32 * D_EMB];   // 16 KB
    for (int i = j; i < rows * D_EMB; i += 256)
        ebuf[i] = emb[(size_t)v0 * D_EMB + i];
    __syncthreads();

    float acc[32];
#pragma unroll
    for (int r = 0; r < 32; ++r) acc[r] = 0.f;

#pragma unroll 8
    for (int d = 0; d < D_EMB; ++d) {
        float wxv = wxw[d * HID + j];    // coalesced
#pragma unroll
        for (int r = 0; r < 32; ++r)
            acc[r] = fmaf(ebuf[r * D_EMB + d], wxv, acc[r]); // LDS broadcast
    }

    const float bb = wxb[j] + whb[j];
    for (int r = 0; r < rows; ++r)
        tab[(size_t)(v0 + r) * HID + j] = acc[r] + bb;       // coalesced
}

__device__ __forceinline__ float fast_tanh(float x) {
    float e2 = __expf(2.f * x);
    return 1.f - 2.f / (e2 + 1.f);
}

// Pure-VALU 16-lane reduction (verified R18: -12%): DPP row_ror adds.
#define DPP_RADD(ACC, N)                                                    \
    asm("v_add_f32 %0, %0, %0 row_ror:" #N " row_mask:0xf bank_mask:0xf"    \
        : "+v"(ACC))

// Barrier WITHOUT the vmcnt(0) drain __syncthreads forces. Loop has no
// global writes; h goes through LDS (lgkmcnt). The in-flight ax prefetch
// load may legally cross the barrier (its consumer has a compiler-counted
// vmcnt wait next step). "memory" clobber pins LDS op ordering.
#define BARRIER_LDS()                                                       \
    asm volatile("s_waitcnt lgkmcnt(0)\n\ts_barrier" ::: "memory")

// ---------------------------------------------------------------------------
// Kernel 2 (main): one block per batch row, 1024 threads (16 waves, 4/SIMD).
// R18 base (1366us: swizzled h reads, DPP rotate-reduce, 0 conflicts) with
// three stall-attacking changes (R12 reinterpretation: the loop has ~500
// cyc/step of latency slack, NOT hidden instructions):
//  1. lgkmcnt-only barrier (no vmcnt drain -> ax gather rides across).
//  2. FMA chains split 16->8 deep (8 accumulators, merge before DPP).
//  3. x4 time unroll.
// Thread (cg = tid>>4, kg = tid&15) owns cols [cg*4, cg*4+4) over k in
// [kg*16, kg*16+16). Bank swizzle rot=(kg>>2)&3: conflict-free (measured).
// ---------------------------------------------------------------------------
__global__ __launch_bounds__(1024, 1)
void rnn_main_kernel(const int*   __restrict__ batch,
                     const float* __restrict__ whw,
                     const float* __restrict__ clfw,
                     const float* __restrict__ clfb,
                     const float* __restrict__ ax_tab,
                     float*       __restrict__ out)
{
    const int b   = blockIdx.x;
    const int tid = threadIdx.x;
    const int kg  = tid & 15;            // k-group: k in [kg*16, kg*16+16)
    const int cg  = tid >> 4;            // col-group: cols [cg*4, cg*4+4)
    const int c0  = cg * 4;
    const int kb  = kg * 16;
    const int rot = (kg >> 2) & 3;       // bank-swizzle rotation
    const int q   = kg & 3;              // which of the 4 cols this lane picks

    __shared__ float hbuf[2][HID];       // double-buffered hidden state
    __shared__ float sbuf[2][HID];       // epilogue scratch

    // --- one-time weight load: W[e][m][i] = wh_w[kb+((e+rot)&3)*4+m][c0+i] ---
    float W[4][4][4];
#pragma unroll
    for (int e = 0; e < 4; ++e) {
        const int swz = (e + rot) & 3;
#pragma unroll
        for (int m = 0; m < 4; ++m) {
            const int k = kb + swz * 4 + m;
            const float4 w4 = *(const float4*)&whw[(size_t)k * HID + c0];
            W[e][m][0] = w4.x; W[e][m][1] = w4.y;
            W[e][m][2] = w4.z; W[e][m][3] = w4.w;
        }
    }
    // Pin once: asm redefines each value -> loads cannot be rematerialized.
#pragma unroll
    for (int e = 0; e < 4; ++e)
#pragma unroll
        for (int m = 0; m < 4; ++m)
            asm volatile("" : "+v"(W[e][m][0]), "+v"(W[e][m][1]),
                              "+v"(W[e][m][2]), "+v"(W[e][m][3]));

    // LDS byte offsets of the 4 swizzled float4 reads (within one h buffer).
    int lds_off[4];
#pragma unroll
    for (int e = 0; e < 4; ++e) lds_off[e] = kg * 64 + ((e + rot) & 3) * 16;

    const int  mycol = c0 + q;           // column this lane selects / writes
    const bool wr    = (kg < 4);         // lanes 0..3 of each row write

    if (tid < HID) hbuf[0][tid] = 0.f;

    const int* brow = batch + (size_t)b * T_LEN;
    const float* axp = ax_tab + mycol;   // 32-bit offsets: tok*256 elems
    int tok_n = brow[0];
    float axv = axp[(unsigned)tok_n * 256u];           // ax for t=0
    tok_n = brow[1];
    __syncthreads();

#define RNN_STEP(CUR, NXT, TT)                                              \
    {                                                                       \
        const int tok_nn = ((TT) + 2 < T_LEN) ? brow[(TT) + 2] : 0;         \
        const float ax_n = axp[(unsigned)tok_n * 256u];                     \
        float accA[4], accB[4];                                             \
        const char* hb = (const char*)&hbuf[CUR][0];                        \
        {   /* e = 0 initializes chain A */                                 \
            const float4 h4 = *(const float4*)(hb + lds_off[0]);            \
            const float hm[4] = {h4.x, h4.y, h4.z, h4.w};                   \
            _Pragma("unroll")                                               \
            for (int i = 0; i < 4; ++i) accA[i] = hm[0] * W[0][0][i];       \
            _Pragma("unroll")                                               \
            for (int m = 1; m < 4; ++m)                                     \
                _Pragma("unroll")                                           \
                for (int i = 0; i < 4; ++i)                                 \
                    accA[i] = fmaf(hm[m], W[0][m][i], accA[i]);             \
        }                                                                   \
        {   /* e = 1 continues chain A */                                   \
            const float4 h4 = *(const float4*)(hb + lds_off[1]);            \
            const float hm[4] = {h4.x, h4.y, h4.z, h4.w};                   \
            _Pragma("unroll")                                               \
            for (int m = 0; m < 4; ++m)                                     \
                _Pragma("unroll")                                           \
                for (int i = 0; i < 4; ++i)                                 \
                    accA[i] = fmaf(hm[m], W[1][m][i], accA[i]);             \
        }                                                                   \
        {   /* e = 2 initializes chain B */                                 \
            const float4 h4 = *(const float4*)(hb + lds_off[2]);            \
            const float hm[4] = {h4.x, h4.y, h4.z, h4.w};                   \
            _Pragma("unroll")                                               \
            for (int i = 0; i < 4; ++i) accB[i] = hm[0] * W[2][0][i];       \
            _Pragma("unroll")                                               \
            for (int m = 1; m < 4; ++m)                                     \
                _Pragma("unroll")                                           \
                for (int i = 0; i < 4; ++i)                                 \
                    accB[i] = fmaf(hm[m], W[2][m][i], accB[i]);             \
        }                                                                   \
        {   /* e = 3 continues chain B */                                   \
            const float4 h4 = *(const float4*)(hb + lds_off[3]);            \
            const float hm[4] = {h4.x, h4.y, h4.z, h4.w};                   \
            _Pragma("unroll")                                               \
            for (int m = 0; m < 4; ++m)                                     \
                _Pragma("unroll")                                           \
                for (int i = 0; i < 4; ++i)                                 \
                    accB[i] = fmaf(hm[m], W[3][m][i], accB[i]);             \
        }                                                                   \
        float acc[4];                                                       \
        _Pragma("unroll")                                                   \
        for (int i = 0; i < 4; ++i) acc[i] = accA[i] + accB[i];             \
        /* DPP rotate-reduce over the 16-lane row: 4 independent chains */  \
        _Pragma("unroll")                                                   \
        for (int i = 0; i < 4; ++i) {                                       \
            DPP_RADD(acc[i], 8);                                            \
            DPP_RADD(acc[i], 4);                                            \
            DPP_RADD(acc[i], 2);                                            \
            DPP_RADD(acc[i], 1);                                            \
        }                                                                   \
        /* loop-invariant-mask selects: lane takes acc[q] */                \
        const float r01 = (q & 1) ? acc[1] : acc[0];                        \
        const float r23 = (q & 1) ? acc[3] : acc[2];                        \
        const float res = (q & 2) ? r23 : r01;                              \
        const float hnew = fast_tanh(res + axv);                            \
        if (wr) hbuf[NXT][mycol] = hnew;                                    \
        BARRIER_LDS();                                                      \
        axv   = ax_n;                                                       \
        tok_n = tok_nn;                                                     \
    }

    for (int t = 0; t < T_LEN; t += 4) {
        RNN_STEP(0, 1, t)
        RNN_STEP(1, 0, t + 1)
        RNN_STEP(0, 1, t + 2)
        RNN_STEP(1, 0, t + 3)
    }
#undef RNN_STEP

    // --- epilogue: out[b][c] = sum_j h[j] * clf_w[j][c] + clf_b[c] ---
    // After a multiple-of-4 number of steps the final h is in hbuf[0].
    if (tid < HID) {
        const float h = hbuf[0][tid];
        sbuf[0][tid] = h * clfw[tid * N_CLS + 0];
        sbuf[1][tid] = h * clfw[tid * N_CLS + 1];
    }
    __syncthreads();
    if (tid < 64) {
        float v = sbuf[0][tid] + sbuf[0][tid + 64] +
                  sbuf[0][tid + 128] + sbuf[0][tid + 192];
#pragma unroll
        for (int off = 32; off > 0; off >>= 1) v += __shfl_xor(v, off);
        if (tid == 0) out[b * N_CLS + 0] = v + clfb[0];
    } else if (tid < 128) {
        const int l = tid - 64;
        float v = sbuf[1][l] + sbuf[1][l + 64] +
                  sbuf[1][l + 128] + sbuf[1][l + 192];
#pragma unroll
        for (int off = 32; off > 0; off >>= 1) v += __shfl_xor(v, off);
        if (l == 0) out[b * N_CLS + 1] = v + clfb[1];
    }
}

// ---------------------------------------------------------------------------
// Fallback (workspace too small for the 51.5 MB table).
// ---------------------------------------------------------------------------
__global__ __launch_bounds__(512, 2)
void rnn_fallback_kernel(const int*   __restrict__ batch,
                         const float* __restrict__ emb,
                         const float* __restrict__ wxw,
                         const float* __restrict__ wxb,
                         const float* __restrict__ whw,
                         const float* __restrict__ whb,
                         const float* __restrict__ clfw,
                         const float* __restrict__ clfb,
                         float*       __restrict__ out)
{
    const int b    = blockIdx.x;
    const int tid  = threadIdx.x;
    const int j    = tid >> 1;
    const int half = tid & 1;
    const int k0   = half * 128;

    __shared__ float hbuf[2][HID];
    __shared__ float ebuf[2][D_EMB];

    float w[128];
#pragma unroll
    for (int k = 0; k < 128; ++k)
        w[k] = whw[(size_t)(k0 + k) * HID + j];

    float wx[64];
#pragma unroll
    for (int d = 0; d < 64; ++d)
        wx[d] = wxw[(size_t)(half * 64 + d) * HID + j];

    const float bj  = whb[j];
    const float axb = wxb[j];

    if (tid < HID) hbuf[0][tid] = 0.f;

    const int* brow = batch + (size_t)b * T_LEN;

    int tok_n = brow[0];
    if (tid < D_EMB) ebuf[0][tid] = emb[(size_t)tok_n * D_EMB + tid];
    tok_n = brow[1];
    __syncthreads();

    float h_j = 0.f;
    int cur = 0;
    for (int t = 0; t < T_LEN; ++t) {
        const int nxt = cur ^ 1;
        const int tok_nn = (t + 2 < T_LEN) ? brow[t + 2] : 0;
        float ev = 0.f;
        if (t + 1 < T_LEN && tid < D_EMB)
            ev = emb[(size_t)tok_n * D_EMB + tid];

        float a0 = 0.f, a1 = 0.f, a2 = 0.f, a3 = 0.f;
        const float4* hv = (const float4*)&hbuf[cur][k0];
#pragma unroll
        for (int i = 0; i < 32; ++i) {
            float4 h4 = hv[i];
            a0 = fmaf(h4.x, w[4 * i + 0], a0);
            a1 = fmaf(h4.y, w[4 * i + 1], a1);
            a2 = fmaf(h4.z, w[4 * i + 2], a2);
            a3 = fmaf(h4.w, w[4 * i + 3], a3);
        }
        const float4* evv = (const float4*)&ebuf[cur][half * 64];
#pragma unroll
        for (int i = 0; i < 16; ++i) {
            float4 e4 = evv[i];
            a0 = fmaf(e4.x, wx[4 * i + 0], a0);
            a1 = fmaf(e4.y, wx[4 * i + 1], a1);
            a2 = fmaf(e4.z, wx[4 * i + 2], a2);
            a3 = fmaf(e4.w, wx[4 * i + 3], a3);
        }
        float s = (a0 + a1) + (a2 + a3);
        s += __shfl_xor(s, 1);

        h_j = fast_tanh(s + bj + axb);

        if (half == 0) hbuf[nxt][j] = h_j;
        if (t + 1 < T_LEN && tid < D_EMB) ebuf[nxt][tid] = ev;
        __syncthreads();

        tok_n = tok_nn;
        cur   = nxt;
    }

    if (half == 0) {
        hbuf[0][j] = h_j * clfw[j * N_CLS + 0];
        hbuf[1][j] = h_j * clfw[j * N_CLS + 1];
    }
    __syncthreads();
    if (tid < 64) {
        float v = hbuf[0][tid] + hbuf[0][tid + 64] +
                  hbuf[0][tid + 128] + hbuf[0][tid + 192];
#pragma unroll
        for (int off = 32; off > 0; off >>= 1) v += __shfl_xor(v, off);
        if (tid == 0) out[b * N_CLS + 0] = v + clfb[0];
    } else if (tid < 128) {
        const int l = tid - 64;
        float v = hbuf[1][l] + hbuf[1][l + 64] +
                  hbuf[1][l + 128] + hbuf[1][l + 192];
#pragma unroll
        for (int off = 32; off > 0; off >>= 1) v += __shfl_xor(v, off);
        if (l == 0) out[b * N_CLS + 1] = v + clfb[1];
    }
}

// ---------------------------------------------------------------------------
extern "C" void kernel_launch(void* const* d_in, const int* in_sizes, int n_in,
                              void* d_out, int out_size, void* d_ws, size_t ws_size,
                              hipStream_t stream)
{
    const int*   batch = (const int*)  d_in[0];
    const float* emb   = (const float*)d_in[1];
    const float* wxw   = (const float*)d_in[2];
    const float* wxb   = (const float*)d_in[3];
    const float* whw   = (const float*)d_in[4];
    const float* whb   = (const float*)d_in[5];
    const float* clfw  = (const float*)d_in[6];
    const float* clfb  = (const float*)d_in[7];
    float* out = (float*)d_out;

    const size_t tab_bytes = (size_t)VOCAB * HID * sizeof(float);
    if (ws_size >= tab_bytes) {
        float* tab = (float*)d_ws;
        tabax_kernel<<<(VOCAB + 31) / 32, 256, 0, stream>>>(emb, wxw, wxb, whb, tab);
        rnn_main_kernel<<<BSZ, 1024, 0, stream>>>(batch, whw, clfw, clfb, tab, out);
    } else {
        rnn_fallback_kernel<<<BSZ, 512, 0, stream>>>(batch, emb, wxw, wxb, whw, whb,
                                                     clfw, clfb, out);
    }
}

// Round 21
// 1270.797 us; speedup vs baseline: 1.6307x; 1.1047x over previous
//
#include <hip/hip_runtime.h>
#include <hip/hip_bf16.h>

// Problem constants (match reference).
#define VOCAB  50257
#define D_EMB  128
#define HID    256
#define N_CLS  2
#define BSZ    256
#define T_LEN  2048

// ---------------------------------------------------------------------------
// Kernel 1: tab[v][j] = sum_d emb_table[v][d] * wx_w[d][j] + wx_b[j] + wh_b[j]
// ---------------------------------------------------------------------------
__global__ __launch_bounds__(256)
void tabax_kernel(const float* __restrict__ emb,
                  const float* __restrict__ wxw,
                  const float* __restrict__ wxb,
                  const float* __restrict__ whb,
                  float* __restrict__ tab)
{
    const int j  = threadIdx.x;          // output unit 0..255
    const int v0 = blockIdx.x * 32;
    const int rows = min(32, VOCAB - v0);

    __shared__ float ebuf[32 * D_EMB];   // 16 KB
    for (int i = j; i < rows * D_EMB; i += 256)
        ebuf[i] = emb[(size_t)v0 * D_EMB + i];
    __syncthreads();

    float acc[32];
#pragma unroll
    for (int r = 0; r < 32; ++r) acc[r] = 0.f;

#pragma unroll 8
    for (int d = 0; d < D_EMB; ++d) {
        float wxv = wxw[d * HID + j];    // coalesced
#pragma unroll
        for (int r = 0; r < 32; ++r)
            acc[r] = fmaf(ebuf[r * D_EMB + d], wxv, acc[r]); // LDS broadcast
    }

    const float bb = wxb[j] + whb[j];
    for (int r = 0; r < rows; ++r)
        tab[(size_t)(v0 + r) * HID + j] = acc[r] + bb;       // coalesced
}

// Fast tanh WITHOUT IEEE division: harness compiles with plain -O3 (no
// fast-math), so `2/(e+1)` was emitting div_scale/div_fmas/div_fixup
// (~6-8 insts). v_rcp_f32 is 1ulp -> tanh error ~1e-7, absmax unaffected.
__device__ __forceinline__ float fast_tanh(float x) {
    float e2 = __expf(2.f * x);                    // 2 mul + v_exp
    float r  = __builtin_amdgcn_rcpf(e2 + 1.f);    // add + v_rcp
    return fmaf(-2.f, r, 1.f);                     // fma
}

// --- DPP reduce primitives (all pure VALU; verified lever in R18: -12%) ---
// sel-pair add with DPP move on src0 (the sent value):
#define DPP_ADD_ROR8(DST, SEND, KEEP)                                       \
    asm("v_add_f32 %0, %1, %2 row_ror:8 row_mask:0xf bank_mask:0xf"         \
        : "=v"(DST) : "v"(SEND), "v"(KEEP))
#define DPP_ADD_HMIR(DST, SEND, KEEP)                                       \
    asm("v_add_f32 %0, %1, %2 row_half_mirror row_mask:0xf bank_mask:0xf"   \
        : "=v"(DST) : "v"(SEND), "v"(KEEP))
#define DPP_QADD1(ACC)                                                      \
    asm("v_add_f32 %0, %0, %0 quad_perm:[1,0,3,2] row_mask:0xf "            \
        "bank_mask:0xf" : "+v"(ACC))
#define DPP_QADD2(ACC)                                                      \
    asm("v_add_f32 %0, %0, %0 quad_perm:[2,3,0,1] row_mask:0xf "            \
        "bank_mask:0xf" : "+v"(ACC))

// ---------------------------------------------------------------------------
// Kernel 2 (main): one block per batch row, 1024 threads (16 waves, 4/SIMD).
// R18 base (1366us) with two issue-count trims (loop is VALU-issue-bound):
//  1. tanh via v_rcp (kills IEEE div, ~-6 insts/step).
//  2. Sel-pair reduce tree, 19 -> 11 ops: L8 = 4 sel + 2 ror8-add (acc 4->2,
//     cols{0,1} in lanes kg<8, {2,3} in kg>=8); L4 = 2 sel + 1
//     half-mirror-add (pairs l<->7-l stay inside each 8-half; acc 2->1,
//     quad q holds col q); 2 quad_perm self-adds finish the quad.
//     Coverage verified: lane 0 sums kg{0,7,8,15}, lane 1 {1,6,9,14},
//     lane 2 {2,5,10,13}, lane 3 {3,4,11,12} -> xor1+xor2 = all 16.
// Writers: kg&3==0; mycol = c0 + (kg>>2) (quad-uniform, axv consistent).
// Thread (cg = tid>>4, kg = tid&15) owns cols [cg*4, cg*4+4) over k in
// [kg*16, kg*16+16). Bank swizzle rot=(kg>>2)&3: conflict-free (measured).
// ---------------------------------------------------------------------------
__global__ __launch_bounds__(1024, 1)
void rnn_main_kernel(const int*   __restrict__ batch,
                     const float* __restrict__ whw,
                     const float* __restrict__ clfw,
                     const float* __restrict__ clfb,
                     const float* __restrict__ ax_tab,
                     float*       __restrict__ out)
{
    const int b   = blockIdx.x;
    const int tid = threadIdx.x;
    const int kg  = tid & 15;            // k-group: k in [kg*16, kg*16+16)
    const int cg  = tid >> 4;            // col-group: cols [cg*4, cg*4+4)
    const int c0  = cg * 4;
    const int kb  = kg * 16;
    const int rot = (kg >> 2) & 3;       // bank-swizzle rotation

    __shared__ float hbuf[2][HID];       // double-buffered hidden state
    __shared__ float sbuf[2][HID];       // epilogue scratch

    // --- one-time weight load: W[e][m][i] = wh_w[kb+((e+rot)&3)*4+m][c0+i] ---
    float W[4][4][4];
#pragma unroll
    for (int e = 0; e < 4; ++e) {
        const int swz = (e + rot) & 3;
#pragma unroll
        for (int m = 0; m < 4; ++m) {
            const int k = kb + swz * 4 + m;
            const float4 w4 = *(const float4*)&whw[(size_t)k * HID + c0];
            W[e][m][0] = w4.x; W[e][m][1] = w4.y;
            W[e][m][2] = w4.z; W[e][m][3] = w4.w;
        }
    }
    // Pin once: asm redefines each value -> loads cannot be rematerialized.
#pragma unroll
    for (int e = 0; e < 4; ++e)
#pragma unroll
        for (int m = 0; m < 4; ++m)
            asm volatile("" : "+v"(W[e][m][0]), "+v"(W[e][m][1]),
                              "+v"(W[e][m][2]), "+v"(W[e][m][3]));

    // LDS byte offsets of the 4 swizzled float4 reads (within one h buffer).
    int lds_off[4];
#pragma unroll
    for (int e = 0; e < 4; ++e) lds_off[e] = kg * 64 + ((e + rot) & 3) * 16;

    const int  mycol = c0 + (kg >> 2);   // column this lane's quad finalizes
    const bool wr    = (kg & 3) == 0;    // 1 lane per quad writes

    if (tid < HID) hbuf[0][tid] = 0.f;

    const int* brow = batch + (size_t)b * T_LEN;
    const float* axp = ax_tab + mycol;   // 32-bit offsets: tok*256 elems
    int tok_n = brow[0];
    float axv = axp[(unsigned)tok_n * 256u];           // ax for t=0
    tok_n = brow[1];
    __syncthreads();

#define RNN_STEP(CUR, NXT, TT)                                              \
    {                                                                       \
        const int tok_nn = ((TT) + 2 < T_LEN) ? brow[(TT) + 2] : 0;         \
        const float ax_n = axp[(unsigned)tok_n * 256u];                     \
        float acc[4];                                                       \
        const char* hb = (const char*)&hbuf[CUR][0];                        \
        {   /* e = 0 initializes acc */                                     \
            const float4 h4 = *(const float4*)(hb + lds_off[0]);            \
            const float hm[4] = {h4.x, h4.y, h4.z, h4.w};                   \
            _Pragma("unroll")                                               \
            for (int i = 0; i < 4; ++i) acc[i] = hm[0] * W[0][0][i];        \
            _Pragma("unroll")                                               \
            for (int m = 1; m < 4; ++m)                                     \
                _Pragma("unroll")                                           \
                for (int i = 0; i < 4; ++i)                                 \
                    acc[i] = fmaf(hm[m], W[0][m][i], acc[i]);               \
        }                                                                   \
        _Pragma("unroll")                                                   \
        for (int e = 1; e < 4; ++e) {                                       \
            const float4 h4 = *(const float4*)(hb + lds_off[e]);            \
            const float hm[4] = {h4.x, h4.y, h4.z, h4.w};                   \
            _Pragma("unroll")                                               \
            for (int m = 0; m < 4; ++m)                                     \
                _Pragma("unroll")                                           \
                for (int i = 0; i < 4; ++i)                                 \
                    acc[i] = fmaf(hm[m], W[e][m][i], acc[i]);               \
        }                                                                   \
        /* sel-pair reduce: L8 (ror8), acc 4 -> 2 */                        \
        const bool hi8 = (kg & 8) != 0;                                     \
        const float sA = hi8 ? acc[0] : acc[2];                             \
        const float kA = hi8 ? acc[2] : acc[0];                             \
        const float sB = hi8 ? acc[1] : acc[3];                             \
        const float kB = hi8 ? acc[3] : acc[1];                             \
        float accA, accB;                                                   \
        DPP_ADD_ROR8(accA, sA, kA);                                         \
        DPP_ADD_ROR8(accB, sB, kB);                                         \
        /* L4 (half-mirror, stays inside each 8-half), acc 2 -> 1 */        \
        const bool hi4 = (kg & 4) != 0;                                     \
        const float sC = hi4 ? accA : accB;                                 \
        const float kC = hi4 ? accB : accA;                                 \
        float accQ;                                                         \
        DPP_ADD_HMIR(accQ, sC, kC);                                         \
        /* quad levels: all 4 lanes of the quad end with the col total */   \
        DPP_QADD1(accQ);                                                    \
        DPP_QADD2(accQ);                                                    \
        const float hnew = fast_tanh(accQ + axv);                           \
        if (wr) hbuf[NXT][mycol] = hnew;                                    \
        __syncthreads();                                                    \
        axv   = ax_n;                                                       \
        tok_n = tok_nn;                                                     \
    }

    for (int t = 0; t < T_LEN; t += 2) {
        RNN_STEP(0, 1, t)
        RNN_STEP(1, 0, t + 1)
    }
#undef RNN_STEP

    // --- epilogue: out[b][c] = sum_j h[j] * clf_w[j][c] + clf_b[c] ---
    // After an even number of steps the final h is in hbuf[0].
    if (tid < HID) {
        const float h = hbuf[0][tid];
        sbuf[0][tid] = h * clfw[tid * N_CLS + 0];
        sbuf[1][tid] = h * clfw[tid * N_CLS + 1];
    }
    __syncthreads();
    if (tid < 64) {
        float v = sbuf[0][tid] + sbuf[0][tid + 64] +
                  sbuf[0][tid + 128] + sbuf[0][tid + 192];
#pragma unroll
        for (int off = 32; off > 0; off >>= 1) v += __shfl_xor(v, off);
        if (tid == 0) out[b * N_CLS + 0] = v + clfb[0];
    } else if (tid < 128) {
        const int l = tid - 64;
        float v = sbuf[1][l] + sbuf[1][l + 64] +
                  sbuf[1][l + 128] + sbuf[1][l + 192];
#pragma unroll
        for (int off = 32; off > 0; off >>= 1) v += __shfl_xor(v, off);
        if (l == 0) out[b * N_CLS + 1] = v + clfb[1];
    }
}

// ---------------------------------------------------------------------------
// Fallback (workspace too small for the 51.5 MB table).
// ---------------------------------------------------------------------------
__global__ __launch_bounds__(512, 2)
void rnn_fallback_kernel(const int*   __restrict__ batch,
                         const float* __restrict__ emb,
                         const float* __restrict__ wxw,
                         const float* __restrict__ wxb,
                         const float* __restrict__ whw,
                         const float* __restrict__ whb,
                         const float* __restrict__ clfw,
                         const float* __restrict__ clfb,
                         float*       __restrict__ out)
{
    const int b    = blockIdx.x;
    const int tid  = threadIdx.x;
    const int j    = tid >> 1;
    const int half = tid & 1;
    const int k0   = half * 128;

    __shared__ float hbuf[2][HID];
    __shared__ float ebuf[2][D_EMB];

    float w[128];
#pragma unroll
    for (int k = 0; k < 128; ++k)
        w[k] = whw[(size_t)(k0 + k) * HID + j];

    float wx[64];
#pragma unroll
    for (int d = 0; d < 64; ++d)
        wx[d] = wxw[(size_t)(half * 64 + d) * HID + j];

    const float bj  = whb[j];
    const float axb = wxb[j];

    if (tid < HID) hbuf[0][tid] = 0.f;

    const int* brow = batch + (size_t)b * T_LEN;

    int tok_n = brow[0];
    if (tid < D_EMB) ebuf[0][tid] = emb[(size_t)tok_n * D_EMB + tid];
    tok_n = brow[1];
    __syncthreads();

    float h_j = 0.f;
    int cur = 0;
    for (int t = 0; t < T_LEN; ++t) {
        const int nxt = cur ^ 1;
        const int tok_nn = (t + 2 < T_LEN) ? brow[t + 2] : 0;
        float ev = 0.f;
        if (t + 1 < T_LEN && tid < D_EMB)
            ev = emb[(size_t)tok_n * D_EMB + tid];

        float a0 = 0.f, a1 = 0.f, a2 = 0.f, a3 = 0.f;
        const float4* hv = (const float4*)&hbuf[cur][k0];
#pragma unroll
        for (int i = 0; i < 32; ++i) {
            float4 h4 = hv[i];
            a0 = fmaf(h4.x, w[4 * i + 0], a0);
            a1 = fmaf(h4.y, w[4 * i + 1], a1);
            a2 = fmaf(h4.z, w[4 * i + 2], a2);
            a3 = fmaf(h4.w, w[4 * i + 3], a3);
        }
        const float4* evv = (const float4*)&ebuf[cur][half * 64];
#pragma unroll
        for (int i = 0; i < 16; ++i) {
            float4 e4 = evv[i];
            a0 = fmaf(e4.x, wx[4 * i + 0], a0);
            a1 = fmaf(e4.y, wx[4 * i + 1], a1);
            a2 = fmaf(e4.z, wx[4 * i + 2], a2);
            a3 = fmaf(e4.w, wx[4 * i + 3], a3);
        }
        float s = (a0 + a1) + (a2 + a3);
        s += __shfl_xor(s, 1);

        h_j = fast_tanh(s + bj + axb);

        if (half == 0) hbuf[nxt][j] = h_j;
        if (t + 1 < T_LEN && tid < D_EMB) ebuf[nxt][tid] = ev;
        __syncthreads();

        tok_n = tok_nn;
        cur   = nxt;
    }

    if (half == 0) {
        hbuf[0][j] = h_j * clfw[j * N_CLS + 0];
        hbuf[1][j] = h_j * clfw[j * N_CLS + 1];
    }
    __syncthreads();
    if (tid < 64) {
        float v = hbuf[0][tid] + hbuf[0][tid + 64] +
                  hbuf[0][tid + 128] + hbuf[0][tid + 192];
#pragma unroll
        for (int off = 32; off > 0; off >>= 1) v += __shfl_xor(v, off);
        if (tid == 0) out[b * N_CLS + 0] = v + clfb[0];
    } else if (tid < 128) {
        const int l = tid - 64;
        float v = hbuf[1][l] + hbuf[1][l + 64] +
                  hbuf[1][l + 128] + hbuf[1][l + 192];
#pragma unroll
        for (int off = 32; off > 0; off >>= 1) v += __shfl_xor(v, off);
        if (l == 0) out[b * N_CLS + 1] = v + clfb[1];
    }
}

// ---------------------------------------------------------------------------
extern "C" void kernel_launch(void* const* d_in, const int* in_sizes, int n_in,
                              void* d_out, int out_size, void* d_ws, size_t ws_size,
                              hipStream_t stream)
{
    const int*   batch = (const int*)  d_in[0];
    const float* emb   = (const float*)d_in[1];
    const float* wxw   = (const float*)d_in[2];
    const float* wxb   = (const float*)d_in[3];
    const float* whw   = (const float*)d_in[4];
    const float* whb   = (const float*)d_in[5];
    const float* clfw  = (const float*)d_in[6];
    const float* clfb  = (const float*)d_in[7];
    float* out = (float*)d_out;

    const size_t tab_bytes = (size_t)VOCAB * HID * sizeof(float);
    if (ws_size >= tab_bytes) {
        float* tab = (float*)d_ws;
        tabax_kernel<<<(VOCAB + 31) / 32, 256, 0, stream>>>(emb, wxw, wxb, whb, tab);
        rnn_main_kernel<<<BSZ, 1024, 0, stream>>>(batch, whw, clfw, clfb, tab, out);
    } else {
        rnn_fallback_kernel<<<BSZ, 512, 0, stream>>>(batch, emb, wxw, wxb, whw, whb,
                                                     clfw, clfb, out);
    }
}

// Round 22
// 1180.596 us; speedup vs baseline: 1.7553x; 1.0764x over previous
//
#include <hip/hip_runtime.h>
#include <hip/hip_bf16.h>

// Problem constants (match reference).
#define VOCAB  50257
#define D_EMB  128
#define HID    256
#define N_CLS  2
#define BSZ    256
#define T_LEN  2048

typedef float f16v __attribute__((ext_vector_type(16)));   // 16 f32 = 16 VGPR tuple

// ---------------------------------------------------------------------------
// Kernel 1: tab[v][j] = sum_d emb_table[v][d] * wx_w[d][j] + wx_b[j] + wh_b[j]
// ---------------------------------------------------------------------------
__global__ __launch_bounds__(256)
void tabax_kernel(const float* __restrict__ emb,
                  const float* __restrict__ wxw,
                  const float* __restrict__ wxb,
                  const float* __restrict__ whb,
                  float* __restrict__ tab)
{
    const int j  = threadIdx.x;          // output unit 0..255
    const int v0 = blockIdx.x * 32;
    const int rows = min(32, VOCAB - v0);

    __shared__ float ebuf[32 * D_EMB];   // 16 KB
    for (int i = j; i < rows * D_EMB; i += 256)
        ebuf[i] = emb[(size_t)v0 * D_EMB + i];
    __syncthreads();

    float acc[32];
#pragma unroll
    for (int r = 0; r < 32; ++r) acc[r] = 0.f;

#pragma unroll 8
    for (int d = 0; d < D_EMB; ++d) {
        float wxv = wxw[d * HID + j];    // coalesced
#pragma unroll
        for (int r = 0; r < 32; ++r)
            acc[r] = fmaf(ebuf[r * D_EMB + d], wxv, acc[r]); // LDS broadcast
    }

    const float bb = wxb[j] + whb[j];
    for (int r = 0; r < rows; ++r)
        tab[(size_t)(v0 + r) * HID + j] = acc[r] + bb;       // coalesced
}

// Fast tanh without IEEE division (R21 win): v_rcp is 1ulp.
__device__ __forceinline__ float fast_tanh(float x) {
    float e2 = __expf(2.f * x);
    float r  = __builtin_amdgcn_rcpf(e2 + 1.f);
    return fmaf(-2.f, r, 1.f);
}

// --- DPP reduce primitives (verified R18/R21) ---
#define DPP_ADD_ROR8(DST, SEND, KEEP)                                       \
    asm("v_add_f32 %0, %1, %2 row_ror:8 row_mask:0xf bank_mask:0xf"         \
        : "=v"(DST) : "v"(SEND), "v"(KEEP))
#define DPP_ADD_HMIR(DST, SEND, KEEP)                                       \
    asm("v_add_f32 %0, %1, %2 row_half_mirror row_mask:0xf bank_mask:0xf"   \
        : "=v"(DST) : "v"(SEND), "v"(KEEP))
#define DPP_QADD1(ACC)                                                      \
    asm("v_add_f32 %0, %0, %0 quad_perm:[1,0,3,2] row_mask:0xf "            \
        "bank_mask:0xf" : "+v"(ACC))
#define DPP_QADD2(ACC)                                                      \
    asm("v_add_f32 %0, %0, %0 quad_perm:[2,3,0,1] row_mask:0xf "            \
        "bank_mask:0xf" : "+v"(ACC))

// ---------------------------------------------------------------------------
// Kernel 2 (main): one block per batch row, 1024 threads (16 waves, 4/SIMD).
// R21 base (1270us) with ONE change: W stored as 4 x 16-wide register
// TUPLES (ext_vector_type(16)) instead of 64 scalar floats.
// Rationale: R7-R21 all showed the RA homing scalar W in AGPRs and paying
// ~64 v_accvgpr_read/step (~512 cyc/SIMD/step = 34% of runtime; VALU is
// issue-saturated). A 16-wide tuple is allocated as ONE contiguous unit;
// compile-time element extracts from an arch-VGPR tuple are direct register
// references (zero instructions). Decisive counter: VGPR_Count 44 -> ~110.
// Everything else identical: swizzled h reads (0 conflicts), 11-op DPP
// sel-pair reduce, rcp-tanh, x2 unroll, ax prefetch.
// ---------------------------------------------------------------------------
__global__ __launch_bounds__(1024, 1)
void rnn_main_kernel(const int*   __restrict__ batch,
                     const float* __restrict__ whw,
                     const float* __restrict__ clfw,
                     const float* __restrict__ clfb,
                     const float* __restrict__ ax_tab,
                     float*       __restrict__ out)
{
    const int b   = blockIdx.x;
    const int tid = threadIdx.x;
    const int kg  = tid & 15;            // k-group: k in [kg*16, kg*16+16)
    const int cg  = tid >> 4;            // col-group: cols [cg*4, cg*4+4)
    const int c0  = cg * 4;
    const int kb  = kg * 16;
    const int rot = (kg >> 2) & 3;       // bank-swizzle rotation

    __shared__ float hbuf[2][HID];       // double-buffered hidden state
    __shared__ float sbuf[2][HID];       // epilogue scratch

    // --- one-time weight load into 4 register tuples:
    // Wt[e][m*4+i] = wh_w[kb+((e+rot)&3)*4+m][c0+i]
    f16v Wt[4];
#pragma unroll
    for (int e = 0; e < 4; ++e) {
        const int swz = (e + rot) & 3;
#pragma unroll
        for (int m = 0; m < 4; ++m) {
            const int k = kb + swz * 4 + m;
            const float4 w4 = *(const float4*)&whw[(size_t)k * HID + c0];
            Wt[e][m * 4 + 0] = w4.x;
            Wt[e][m * 4 + 1] = w4.y;
            Wt[e][m * 4 + 2] = w4.z;
            Wt[e][m * 4 + 3] = w4.w;
        }
    }
    // Pin each tuple (single 16-wide "v" operand): no rematerialization,
    // and the tuple must materialize contiguously in the register file.
    asm volatile("" : "+v"(Wt[0]));
    asm volatile("" : "+v"(Wt[1]));
    asm volatile("" : "+v"(Wt[2]));
    asm volatile("" : "+v"(Wt[3]));

    // LDS byte offsets of the 4 swizzled float4 reads (within one h buffer).
    int lds_off[4];
#pragma unroll
    for (int e = 0; e < 4; ++e) lds_off[e] = kg * 64 + ((e + rot) & 3) * 16;

    const int  mycol = c0 + (kg >> 2);   // column this lane's quad finalizes
    const bool wr    = (kg & 3) == 0;    // 1 lane per quad writes

    if (tid < HID) hbuf[0][tid] = 0.f;

    const int* brow = batch + (size_t)b * T_LEN;
    const float* axp = ax_tab + mycol;   // 32-bit offsets: tok*256 elems
    int tok_n = brow[0];
    float axv = axp[(unsigned)tok_n * 256u];           // ax for t=0
    tok_n = brow[1];
    __syncthreads();

#define RNN_STEP(CUR, NXT, TT)                                              \
    {                                                                       \
        const int tok_nn = ((TT) + 2 < T_LEN) ? brow[(TT) + 2] : 0;         \
        const float ax_n = axp[(unsigned)tok_n * 256u];                     \
        float acc[4];                                                       \
        const char* hb = (const char*)&hbuf[CUR][0];                        \
        {   /* e = 0 initializes acc */                                     \
            const float4 h4 = *(const float4*)(hb + lds_off[0]);            \
            const float hm[4] = {h4.x, h4.y, h4.z, h4.w};                   \
            _Pragma("unroll")                                               \
            for (int i = 0; i < 4; ++i) acc[i] = hm[0] * Wt[0][i];          \
            _Pragma("unroll")                                               \
            for (int m = 1; m < 4; ++m)                                     \
                _Pragma("unroll")                                           \
                for (int i = 0; i < 4; ++i)                                 \
                    acc[i] = fmaf(hm[m], Wt[0][m * 4 + i], acc[i]);         \
        }                                                                   \
        _Pragma("unroll")                                                   \
        for (int e = 1; e < 4; ++e) {                                       \
            const float4 h4 = *(const float4*)(hb + lds_off[e]);            \
            const float hm[4] = {h4.x, h4.y, h4.z, h4.w};                   \
            _Pragma("unroll")                                               \
            for (int m = 0; m < 4; ++m)                                     \
                _Pragma("unroll")                                           \
                for (int i = 0; i < 4; ++i)                                 \
                    acc[i] = fmaf(hm[m], Wt[e][m * 4 + i], acc[i]);         \
        }                                                                   \
        /* sel-pair reduce: L8 (ror8), acc 4 -> 2 */                        \
        const bool hi8 = (kg & 8) != 0;                                     \
        const float sA = hi8 ? acc[0] : acc[2];                             \
        const float kA = hi8 ? acc[2] : acc[0];                             \
        const float sB = hi8 ? acc[1] : acc[3];                             \
        const float kB = hi8 ? acc[3] : acc[1];                             \
        float accA, accB;                                                   \
        DPP_ADD_ROR8(accA, sA, kA);                                         \
        DPP_ADD_ROR8(accB, sB, kB);                                         \
        /* L4 (half-mirror, stays inside each 8-half), acc 2 -> 1 */        \
        const bool hi4 = (kg & 4) != 0;                                     \
        const float sC = hi4 ? accA : accB;                                 \
        const float kC = hi4 ? accB : accA;                                 \
        float accQ;                                                         \
        DPP_ADD_HMIR(accQ, sC, kC);                                         \
        /* quad levels: all 4 lanes of the quad end with the col total */   \
        DPP_QADD1(accQ);                                                    \
        DPP_QADD2(accQ);                                                    \
        const float hnew = fast_tanh(accQ + axv);                           \
        if (wr) hbuf[NXT][mycol] = hnew;                                    \
        __syncthreads();                                                    \
        axv   = ax_n;                                                       \
        tok_n = tok_nn;                                                     \
    }

    for (int t = 0; t < T_LEN; t += 2) {
        RNN_STEP(0, 1, t)
        RNN_STEP(1, 0, t + 1)
    }
#undef RNN_STEP

    // --- epilogue: out[b][c] = sum_j h[j] * clf_w[j][c] + clf_b[c] ---
    // After an even number of steps the final h is in hbuf[0].
    if (tid < HID) {
        const float h = hbuf[0][tid];
        sbuf[0][tid] = h * clfw[tid * N_CLS + 0];
        sbuf[1][tid] = h * clfw[tid * N_CLS + 1];
    }
    __syncthreads();
    if (tid < 64) {
        float v = sbuf[0][tid] + sbuf[0][tid + 64] +
                  sbuf[0][tid + 128] + sbuf[0][tid + 192];
#pragma unroll
        for (int off = 32; off > 0; off >>= 1) v += __shfl_xor(v, off);
        if (tid == 0) out[b * N_CLS + 0] = v + clfb[0];
    } else if (tid < 128) {
        const int l = tid - 64;
        float v = sbuf[1][l] + sbuf[1][l + 64] +
                  sbuf[1][l + 128] + sbuf[1][l + 192];
#pragma unroll
        for (int off = 32; off > 0; off >>= 1) v += __shfl_xor(v, off);
        if (l == 0) out[b * N_CLS + 1] = v + clfb[1];
    }
}

// ---------------------------------------------------------------------------
// Fallback (workspace too small for the 51.5 MB table).
// ---------------------------------------------------------------------------
__global__ __launch_bounds__(512, 2)
void rnn_fallback_kernel(const int*   __restrict__ batch,
                         const float* __restrict__ emb,
                         const float* __restrict__ wxw,
                         const float* __restrict__ wxb,
                         const float* __restrict__ whw,
                         const float* __restrict__ whb,
                         const float* __restrict__ clfw,
                         const float* __restrict__ clfb,
                         float*       __restrict__ out)
{
    const int b    = blockIdx.x;
    const int tid  = threadIdx.x;
    const int j    = tid >> 1;
    const int half = tid & 1;
    const int k0   = half * 128;

    __shared__ float hbuf[2][HID];
    __shared__ float ebuf[2][D_EMB];

    float w[128];
#pragma unroll
    for (int k = 0; k < 128; ++k)
        w[k] = whw[(size_t)(k0 + k) * HID + j];

    float wx[64];
#pragma unroll
    for (int d = 0; d < 64; ++d)
        wx[d] = wxw[(size_t)(half * 64 + d) * HID + j];

    const float bj  = whb[j];
    const float axb = wxb[j];

    if (tid < HID) hbuf[0][tid] = 0.f;

    const int* brow = batch + (size_t)b * T_LEN;

    int tok_n = brow[0];
    if (tid < D_EMB) ebuf[0][tid] = emb[(size_t)tok_n * D_EMB + tid];
    tok_n = brow[1];
    __syncthreads();

    float h_j = 0.f;
    int cur = 0;
    for (int t = 0; t < T_LEN; ++t) {
        const int nxt = cur ^ 1;
        const int tok_nn = (t + 2 < T_LEN) ? brow[t + 2] : 0;
        float ev = 0.f;
        if (t + 1 < T_LEN && tid < D_EMB)
            ev = emb[(size_t)tok_n * D_EMB + tid];

        float a0 = 0.f, a1 = 0.f, a2 = 0.f, a3 = 0.f;
        const float4* hv = (const float4*)&hbuf[cur][k0];
#pragma unroll
        for (int i = 0; i < 32; ++i) {
            float4 h4 = hv[i];
            a0 = fmaf(h4.x, w[4 * i + 0], a0);
            a1 = fmaf(h4.y, w[4 * i + 1], a1);
            a2 = fmaf(h4.z, w[4 * i + 2], a2);
            a3 = fmaf(h4.w, w[4 * i + 3], a3);
        }
        const float4* evv = (const float4*)&ebuf[cur][half * 64];
#pragma unroll
        for (int i = 0; i < 16; ++i) {
            float4 e4 = evv[i];
            a0 = fmaf(e4.x, wx[4 * i + 0], a0);
            a1 = fmaf(e4.y, wx[4 * i + 1], a1);
            a2 = fmaf(e4.z, wx[4 * i + 2], a2);
            a3 = fmaf(e4.w, wx[4 * i + 3], a3);
        }
        float s = (a0 + a1) + (a2 + a3);
        s += __shfl_xor(s, 1);

        h_j = fast_tanh(s + bj + axb);

        if (half == 0) hbuf[nxt][j] = h_j;
        if (t + 1 < T_LEN && tid < D_EMB) ebuf[nxt][tid] = ev;
        __syncthreads();

        tok_n = tok_nn;
        cur   = nxt;
    }

    if (half == 0) {
        hbuf[0][j] = h_j * clfw[j * N_CLS + 0];
        hbuf[1][j] = h_j * clfw[j * N_CLS + 1];
    }
    __syncthreads();
    if (tid < 64) {
        float v = hbuf[0][tid] + hbuf[0][tid + 64] +
                  hbuf[0][tid + 128] + hbuf[0][tid + 192];
#pragma unroll
        for (int off = 32; off > 0; off >>= 1) v += __shfl_xor(v, off);
        if (tid == 0) out[b * N_CLS + 0] = v + clfb[0];
    } else if (tid < 128) {
        const int l = tid - 64;
        float v = hbuf[1][l] + hbuf[1][l + 64] +
                  hbuf[1][l + 128] + hbuf[1][l + 192];
#pragma unroll
        for (int off = 32; off > 0; off >>= 1) v += __shfl_xor(v, off);
        if (l == 0) out[b * N_CLS + 1] = v + clfb[1];
    }
}

// ---------------------------------------------------------------------------
extern "C" void kernel_launch(void* const* d_in, const int* in_sizes, int n_in,
                              void* d_out, int out_size, void* d_ws, size_t ws_size,
                              hipStream_t stream)
{
    const int*   batch = (const int*)  d_in[0];
    const float* emb   = (const float*)d_in[1];
    const float* wxw   = (const float*)d_in[2];
    const float* wxb   = (const float*)d_in[3];
    const float* whw   = (const float*)d_in[4];
    const float* whb   = (const float*)d_in[5];
    const float* clfw  = (const float*)d_in[6];
    const float* clfb  = (const float*)d_in[7];
    float* out = (float*)d_out;

    const size_t tab_bytes = (size_t)VOCAB * HID * sizeof(float);
    if (ws_size >= tab_bytes) {
        float* tab = (float*)d_ws;
        tabax_kernel<<<(VOCAB + 31) / 32, 256, 0, stream>>>(emb, wxw, wxb, whb, tab);
        rnn_main_kernel<<<BSZ, 1024, 0, stream>>>(batch, whw, clfw, clfb, tab, out);
    } else {
        rnn_fallback_kernel<<<BSZ, 512, 0, stream>>>(batch, emb, wxw, wxb, whw, whb,
                                                     clfw, clfb, out);
    }
}